// Round 8
// baseline (238.612 us; speedup 1.0000x reference)
//
#include <hip/hip_runtime.h>
#include <hip/hip_cooperative_groups.h>
#include <stdint.h>

namespace cg = cooperative_groups;

#define HH   512
#define WWI  512
#define HWN  (HH*WWI)
#define KK   256
#define WSR  32
#define SSW  64
#define RPB  4                         // rows per front block
#define HALO 5
#define SROWS (RPB + 2*HALO)           // 14
#define NFRONT 128                     // HH/RPB
#define CPB  32                        // candidate slots per front block
#define CAND_CAP 4096                  // NFRONT*CPB
#define NB   256                       // grid blocks (co-resident)

// workspace byte offsets
#define OFF_MAXP   0u
#define OFF_LAB    1048576u
#define OFF_BITS   2097152u            // 256*64*8 = 131072
#define OFF_AREA   2228224u
#define OFF_MSUM   2229248u
#define OFF_WY0    2230272u
#define OFF_WX0    2231296u
#define OFF_FINAL  2232320u
#define OFF_CNT    2233344u
#define OFF_ADJ    2233352u            // 8-aligned; 256*4*8 = 8192
#define OFF_CAND   2241544u            // 8-aligned; 4096*8 = 32768
#define OFF_RANK   2274312u            // 4096*4 = 16384

__device__ __forceinline__ float sigm(float v) {
    return 1.0f / (1.0f + expf(-v));
}

__global__ __launch_bounds__(256) void mega(
        const float* __restrict__ x, const float* __restrict__ wc,
        const float* __restrict__ bc, float* __restrict__ labels,
        float* __restrict__ probs, unsigned int* __restrict__ maxp,
        int* __restrict__ lab, unsigned long long* __restrict__ bits,
        float* __restrict__ areas, float* __restrict__ msum,
        int* __restrict__ iy0, int* __restrict__ ix0,
        int* __restrict__ fmap, int* __restrict__ cnt,
        unsigned long long* __restrict__ adj,
        unsigned long long* __restrict__ cand, int* __restrict__ rankbuf) {
    cg::grid_group gg = cg::this_grid();
    int tid = threadIdx.x, bid = blockIdx.x;

    __shared__ float vm[RPB][WWI];                 // 8 KB (P1)
    __shared__ unsigned long long kl[256];         // 2 KB (P2)
    __shared__ unsigned long long rowA[64];        // 512 B (P4)
    __shared__ unsigned long long adjS[KK][4];     // 8 KB (P5)
    __shared__ int lbl[KK];                        // 1 KB (P5)
    __shared__ unsigned char rem[KK];              // 256 B (P5)
    __shared__ int lcnt, changed, say0, sax0;
    __shared__ float sA, sM;

    const float* x4 = x + 4 * HWN;

    // ---------------- P1: front (blocks 0..127) + zero-fills (128..255) ----
    if (bid < NFRONT) {
        int r0 = bid * RPB;
        if (tid == 0) lcnt = 0;
        if (tid < CPB) cand[bid * CPB + tid] = 0ull;
        float s0[SROWS], s1[SROWS];
        #pragma unroll
        for (int hr = 0; hr < SROWS; ++hr) {
            int gr = r0 - HALO + hr; gr = gr < 0 ? 0 : (gr > HH-1 ? HH-1 : gr);
            const float* row = x4 + gr * WWI;
            s0[hr] = sigm(row[tid]);
            s1[hr] = sigm(row[tid + 256]);
        }
        #pragma unroll
        for (int rr = 0; rr < RPB; ++rr) {
            float a = s0[rr], b = s1[rr];
            #pragma unroll
            for (int d = 1; d < 11; ++d) { a = fmaxf(a, s0[rr+d]); b = fmaxf(b, s1[rr+d]); }
            vm[rr][tid] = a; vm[rr][tid + 256] = b;
        }
        __syncthreads();
        #pragma unroll
        for (int rr = 0; rr < RPB; ++rr) {
            int gy = r0 + rr;
            {
                int c = tid;
                float m = s0[rr + HALO];
                if (m > 0.7f) {
                    int c0 = c-5 < 0 ? 0 : c-5, c1 = c+5;
                    float v = -1.0f;
                    for (int cc2 = c0; cc2 <= c1; ++cc2) v = fmaxf(v, vm[rr][cc2]);
                    if (m == v) {
                        int slot = atomicAdd(&lcnt, 1);
                        if (slot < CPB) {
                            unsigned p = (unsigned)(gy * WWI + c);
                            cand[bid * CPB + slot] =
                                ((unsigned long long)__float_as_uint(m) << 32) |
                                (unsigned long long)(0xFFFFFFFFu - p);
                        }
                    }
                }
            }
            {
                int c = tid + 256;
                float m = s1[rr + HALO];
                if (m > 0.7f) {
                    int c0 = c-5, c1 = c+5 > 511 ? 511 : c+5;
                    float v = -1.0f;
                    for (int cc2 = c0; cc2 <= c1; ++cc2) v = fmaxf(v, vm[rr][cc2]);
                    if (m == v) {
                        int slot = atomicAdd(&lcnt, 1);
                        if (slot < CPB) {
                            unsigned p = (unsigned)(gy * WWI + c);
                            cand[bid * CPB + slot] =
                                ((unsigned long long)__float_as_uint(m) << 32) |
                                (unsigned long long)(0xFFFFFFFFu - p);
                        }
                    }
                }
            }
        }
    } else {
        int gt = (bid - NFRONT) * 256 + tid;       // 0..32767
        #pragma unroll
        for (int i = 0; i < 8; ++i) {
            maxp[gt + i * 32768] = 0u;
            lab[gt + i * 32768] = 0;
        }
        if (gt < KK * 64) bits[gt] = 0ull;
        if (gt < CAND_CAP) rankbuf[gt] = 0;
        if (gt < KK) { areas[gt] = 0.0f; msum[gt] = 0.0f; iy0[gt] = 0; ix0[gt] = 0; }
        if (gt == 0) *cnt = 0;
    }
    gg.sync();

    // ---------------- P2: rank tiles (16 x 16 = 256 blocks) ----------------
    {
        int bx = bid & 15, by = bid >> 4;
        int ibase = bx * 256, jbase = by * 256;
        kl[tid] = cand[jbase + tid];
        unsigned long long my = cand[ibase + tid];
        if (by == 0) {
            unsigned long long bal = __ballot(my != 0ull);
            if ((tid & 63) == 0) atomicAdd(cnt, (int)__popcll(bal));
        }
        __syncthreads();
        if (my != 0ull) {
            int r0 = 0, r1 = 0, r2 = 0, r3 = 0, r4 = 0, r5 = 0, r6 = 0, r7 = 0;
            #pragma unroll 4
            for (int j = 0; j < 256; j += 8) {
                unsigned long long a0 = kl[j+0], a1 = kl[j+1], a2 = kl[j+2], a3 = kl[j+3];
                unsigned long long a4 = kl[j+4], a5 = kl[j+5], a6 = kl[j+6], a7 = kl[j+7];
                r0 += (a0 > my); r1 += (a1 > my); r2 += (a2 > my); r3 += (a3 > my);
                r4 += (a4 > my); r5 += (a5 > my); r6 += (a6 > my); r7 += (a7 > my);
            }
            int r = (r0 + r1) + (r2 + r3) + ((r4 + r5) + (r6 + r7));
            if (r) atomicAdd(&rankbuf[ibase + tid], r);
        }
    }
    gg.sync();

    // ---------------- P3: windowed classifier (strided candidates) ---------
    int cclamp = *cnt; if (cclamp > KK) cclamp = KK;
    if (bid >= cclamp) {
        for (int i = tid; i < 4096; i += 256) probs[bid * 4096 + i] = 0.0f;
    }
    {
        float w0 = wc[0], w1 = wc[1], w2 = wc[2], w3 = wc[3], b = bc[0];
        const float* x0 = x;
        const float* x1 = x + HWN;
        const float* x2 = x + 2 * HWN;
        const float* x3 = x + 3 * HWN;
        int lane = tid & 63;
        for (int c = bid; c < CAND_CAP; c += NB) {
            unsigned long long my = cand[c];        // block-uniform
            if (my == 0ull) continue;
            int k = rankbuf[c];                     // block-uniform
            if (k >= KK) continue;
            unsigned pp = 0xFFFFFFFFu - (unsigned)(my & 0xFFFFFFFFull);
            int cy = (int)(pp >> 9), cx = (int)(pp & 511);
            int wy = cy < WSR ? WSR : (cy > HH - WSR ? HH - WSR : cy);
            int wx = cx < WSR ? WSR : (cx > WWI - WSR ? WWI - WSR : cx);
            int gy0 = wy - WSR, gx0 = wx - WSR;
            if (tid == 0) { iy0[k] = gy0; ix0[k] = gx0; sA = 0.0f; sM = 0.0f; }
            __syncthreads();
            float cyf = (float)cy, cxf = (float)cx;
            float aA = 0.0f, aM = 0.0f;
            #pragma unroll 4
            for (int q = 0; q < 16; ++q) {
                int p = (q << 8) + tid;
                int row = p >> 6;                   // uniform per wave
                int col = p & 63;                   // = lane
                int gy = gy0 + row, gx = gx0 + col;
                int g = gy * WWI + gx;
                float gyf = (float)gy;
                float d0 = __fsub_rn(__fadd_rn(x0[g], gyf), cyf);
                float d1 = __fsub_rn(__fadd_rn(x1[g], (float)gx), cxf);
                float s0v = x2[g], s1v = x3[g];
                float t = __fadd_rn(
                            __fadd_rn(
                              __fadd_rn(
                                __fadd_rn(__fmul_rn(w0, d0), __fmul_rn(w1, d1)),
                                __fmul_rn(w2, s0v)),
                              __fmul_rn(w3, s1v)),
                            b);
                float pr = sigm(t);
                probs[k * 4096 + p] = pr;
                bool pass = pr > 0.53f;
                unsigned long long bal = __ballot(pass);
                if (lane == 0) bits[k * 64 + row] = bal;
                if (pass) {
                    aA += 1.0f;
                    aM += sigm(x4[g]);
                    atomicMax(&maxp[g], __float_as_uint(pr));
                }
            }
            #pragma unroll
            for (int off = 32; off; off >>= 1) {
                aA += __shfl_down(aA, off);
                aM += __shfl_down(aM, off);
            }
            if (lane == 0) { atomicAdd(&sA, aA); atomicAdd(&sM, aM); }
            __syncthreads();
            if (tid == 0) { areas[k] = sA; msum[k] = sM; }
        }
    }
    gg.sync();

    // ---------------- P4: winner labeling + pairwise IoU --------------------
    if (bid < cclamp) {
        int k = bid;
        int gy0 = iy0[k], gx0 = ix0[k];
        for (int q = 0; q < 16; ++q) {
            int p = tid + (q << 8);
            float pr = probs[k * 4096 + p];
            if (pr > 0.53f) {
                int r = p >> 6, cc2 = p & 63;
                int g = (gy0 + r) * WWI + gx0 + cc2;
                if (pr >= __uint_as_float(maxp[g])) atomicMax(&lab[g], k + 1);
            }
        }
    }
    {
        int a = bid, b2 = tid;
        if (tid < 64) rowA[tid] = bits[a * 64 + tid];
        if (tid == 0) { say0 = iy0[a]; sax0 = ix0[a]; }
        __syncthreads();
        int ay0 = say0, ax0 = sax0;
        int by0 = iy0[b2], bx0 = ix0[b2];
        int yl = max(ay0, by0), yh = min(ay0 + SSW, by0 + SSW);
        int xl = max(ax0, bx0), xh = min(ax0 + SSW, bx0 + SSW);
        int inter = 0;
        if (yl < yh && xl < xh) {
            int wdt = xh - xl;
            unsigned long long cmask = (wdt >= 64) ? ~0ull : ((1ull << wdt) - 1ull);
            int sa = xl - ax0, sb = xl - bx0;
            for (int y = yl; y < yh; ++y) {
                unsigned long long wa = rowA[y - ay0] >> sa;
                unsigned long long wb = bits[b2 * 64 + (y - by0)] >> sb;
                inter += __popcll(wa & wb & cmask);
            }
        }
        float fi = (float)inter;
        float uni = __fsub_rn(__fadd_rn(areas[a], areas[b2]), fi);
        bool adjb = (fi / fmaxf(uni, 1.0f)) > 0.3f;
        unsigned long long bal = __ballot(adjb);
        if ((tid & 63) == 0) adj[a * 4 + (tid >> 6)] = bal;
    }
    gg.sync();

    // ---------------- P5: connected components (block 0) --------------------
    if (bid == 0) {
        for (int w = 0; w < 4; ++w) adjS[tid][w] = adj[tid * 4 + w];
        lbl[tid] = tid;
        __syncthreads();
        for (int it = 0; it < 32; ++it) {
            int m = KK;
            for (int w = 0; w < 4; ++w) {
                unsigned long long bb = adjS[tid][w];
                while (bb) {
                    int j = __ffsll((unsigned long long)bb) - 1;
                    int v = lbl[(w << 6) | j];
                    m = v < m ? v : m;
                    bb &= bb - 1;
                }
            }
            if (tid == 0) changed = 0;
            __syncthreads();
            if (m != lbl[tid]) { lbl[tid] = m; atomicOr(&changed, 1); }
            __syncthreads();
            if (!changed) break;
        }
        float area = areas[tid];
        bool validf = tid < cclamp;
        float mean = msum[tid] / fmaxf(area, 1.0f);
        rem[tid] = (unsigned char)(!((mean > 0.0f) && (area > 10.0f) && validf));
        __syncthreads();
        int root = lbl[tid];
        int rc = root < 255 ? root : 255;
        fmap[tid] = rem[rc] ? 0 : (root + 1);
    }
    gg.sync();

    // ---------------- P6: final relabel --------------------------------------
    for (int p = bid * 256 + tid; p < HWN; p += NB * 256) {
        int l = lab[p];
        labels[p] = l > 0 ? (float)fmap[l - 1] : 0.0f;
    }
}

extern "C" void kernel_launch(void* const* d_in, const int* in_sizes, int n_in,
                              void* d_out, int out_size, void* d_ws, size_t ws_size,
                              hipStream_t stream) {
    const float* x  = (const float*)d_in[0];
    const float* wc = (const float*)d_in[1];
    const float* bc = (const float*)d_in[2];
    float* labels = (float*)d_out;
    float* probs  = (float*)d_out + HWN;

    char* ws = (char*)d_ws;
    unsigned int*       maxp    = (unsigned int*)(ws + OFF_MAXP);
    int*                lab     = (int*)(ws + OFF_LAB);
    unsigned long long* bits    = (unsigned long long*)(ws + OFF_BITS);
    float*              areas   = (float*)(ws + OFF_AREA);
    float*              msum    = (float*)(ws + OFF_MSUM);
    int*                iy0p    = (int*)(ws + OFF_WY0);
    int*                ix0p    = (int*)(ws + OFF_WX0);
    int*                fmap    = (int*)(ws + OFF_FINAL);
    int*                cnt     = (int*)(ws + OFF_CNT);
    unsigned long long* adj     = (unsigned long long*)(ws + OFF_ADJ);
    unsigned long long* cand    = (unsigned long long*)(ws + OFF_CAND);
    int*                rankbuf = (int*)(ws + OFF_RANK);

    void* args[] = { &x, &wc, &bc, &labels, &probs, &maxp, &lab, &bits,
                     &areas, &msum, &iy0p, &ix0p, &fmap, &cnt, &adj, &cand,
                     &rankbuf };
    hipLaunchCooperativeKernel((const void*)mega, dim3(NB), dim3(256),
                               args, 0, stream);
}

// Round 9
// 78.392 us; speedup vs baseline: 3.0438x; 3.0438x over previous
//
#include <hip/hip_runtime.h>
#include <stdint.h>

#define HH   512
#define WWI  512
#define HWN  (HH*WWI)
#define KK   256
#define WSR  32
#define SSW  64
#define RPB  4                         // rows per front strip block
#define HALO 5
#define SROWS (RPB + 2*HALO)           // 14
#define NFRONT 128                     // HH/RPB
#define CPB  32                        // candidate slots per strip
#define CAND_CAP 4096                  // NFRONT*CPB

// workspace byte offsets
#define OFF_PACKED 0u                  // HWN*8 = 2 MB   (pr_bits<<32 | winner_id)
#define OFF_BITS   2097152u            // 256*64*8 = 128 KB
#define OFF_AREA   2228224u            // 1 KB
#define OFF_MSUM   2229248u            // 1 KB
#define OFF_WY0    2230272u            // 1 KB
#define OFF_WX0    2231296u            // 1 KB
#define OFF_FINAL  2232320u            // 1 KB
#define OFF_DONE   2233344u            // 8 B
#define OFF_ADJ    2233352u            // 8 KB
#define OFF_CAND   2241544u            // 32 KB

__device__ __forceinline__ float sigm(float v) {
    return 1.0f / (1.0f + expf(-v));
}

// Front: blocks [0,128) = sigmoid + separable 11x11 max + peak emit (private
// candidate regions). Blocks [128,256) = all zero-fills (run concurrently).
__global__ __launch_bounds__(256) void k_front(const float* __restrict__ x4,
        unsigned long long* __restrict__ cand,
        unsigned long long* __restrict__ packed,
        unsigned long long* __restrict__ bits,
        float* __restrict__ areas, float* __restrict__ msum,
        int* __restrict__ iy0, int* __restrict__ ix0,
        int* __restrict__ done) {
    int tid = threadIdx.x, bid = blockIdx.x;
    if (bid < NFRONT) {
        __shared__ float vm[RPB][WWI];
        __shared__ int lcnt;
        int r0 = bid * RPB;
        if (tid == 0) lcnt = 0;
        if (tid < CPB) cand[bid * CPB + tid] = 0ull;
        float s0[SROWS], s1[SROWS];
        #pragma unroll
        for (int hr = 0; hr < SROWS; ++hr) {
            int gr = r0 - HALO + hr; gr = gr < 0 ? 0 : (gr > HH-1 ? HH-1 : gr);
            const float* row = x4 + gr * WWI;
            s0[hr] = sigm(row[tid]);
            s1[hr] = sigm(row[tid + 256]);
        }
        #pragma unroll
        for (int rr = 0; rr < RPB; ++rr) {
            float a = s0[rr], b = s1[rr];
            #pragma unroll
            for (int d = 1; d < 11; ++d) { a = fmaxf(a, s0[rr+d]); b = fmaxf(b, s1[rr+d]); }
            vm[rr][tid] = a; vm[rr][tid + 256] = b;
        }
        __syncthreads();
        #pragma unroll
        for (int rr = 0; rr < RPB; ++rr) {
            int gy = r0 + rr;
            {
                int c = tid;
                float m = s0[rr + HALO];
                if (m > 0.7f) {
                    int c0 = c-5 < 0 ? 0 : c-5, c1 = c+5;
                    float v = -1.0f;
                    for (int cc = c0; cc <= c1; ++cc) v = fmaxf(v, vm[rr][cc]);
                    if (m == v) {
                        int slot = atomicAdd(&lcnt, 1);
                        if (slot < CPB) {
                            unsigned p = (unsigned)(gy * WWI + c);
                            cand[bid * CPB + slot] =
                                ((unsigned long long)__float_as_uint(m) << 32) |
                                (unsigned long long)(0xFFFFFFFFu - p);
                        }
                    }
                }
            }
            {
                int c = tid + 256;
                float m = s1[rr + HALO];
                if (m > 0.7f) {
                    int c0 = c-5, c1 = c+5 > 511 ? 511 : c+5;
                    float v = -1.0f;
                    for (int cc = c0; cc <= c1; ++cc) v = fmaxf(v, vm[rr][cc]);
                    if (m == v) {
                        int slot = atomicAdd(&lcnt, 1);
                        if (slot < CPB) {
                            unsigned p = (unsigned)(gy * WWI + c);
                            cand[bid * CPB + slot] =
                                ((unsigned long long)__float_as_uint(m) << 32) |
                                (unsigned long long)(0xFFFFFFFFu - p);
                        }
                    }
                }
            }
        }
    } else {
        int gt = (bid - NFRONT) * 256 + tid;       // [0, 32768)
        #pragma unroll
        for (int i = 0; i < 8; ++i) packed[gt + i * 32768] = 0ull;
        if (gt < KK * 64) bits[gt] = 0ull;
        if (gt < KK) { areas[gt] = 0.0f; msum[gt] = 0.0f; iy0[gt] = 0; ix0[gt] = 0; }
        if (gt == 0) *done = 0;
    }
}

// Windowed classifier per candidate. Block derives its candidate's global
// descending-sort rank by scanning all keys (L2-resident), then computes the
// 64x64 window: coalesced loads, probs store, ballot row-bitmaps, and ONE
// packed 64-bit atomicMax (pr_bits<<32 | id) = winner labeling fused in.
// Tail blocks zero probs for unfilled rank slots.
__global__ __launch_bounds__(256) void k_win2(const float* __restrict__ x,
        const float* __restrict__ wc, const float* __restrict__ bc,
        const unsigned long long* __restrict__ cand,
        float* __restrict__ probs, unsigned long long* __restrict__ packed,
        unsigned long long* __restrict__ bits,
        float* __restrict__ areas, float* __restrict__ msum,
        int* __restrict__ iy0, int* __restrict__ ix0) {
    int bid = blockIdx.x, tid = threadIdx.x;
    int lane = tid & 63, wid = tid >> 6;
    __shared__ int redI[4];
    __shared__ float sA, sM;
    if (bid >= CAND_CAP) {             // tail: zero unfilled prob slots
        int j = bid - CAND_CAP;
        int local = 0;
        for (int i = tid; i < CAND_CAP; i += 256) local += (cand[i] != 0ull);
        #pragma unroll
        for (int off = 32; off; off >>= 1) local += __shfl_down(local, off);
        if (lane == 0) redI[wid] = local;
        __syncthreads();
        int cnt = redI[0] + redI[1] + redI[2] + redI[3];
        if (cnt > KK) cnt = KK;
        if (j >= cnt) for (int i = tid; i < 4096; i += 256) probs[j * 4096 + i] = 0.0f;
        return;
    }
    unsigned long long my = cand[bid];
    if (my == 0ull) return;
    int local = 0;
    for (int i = tid; i < CAND_CAP; i += 256) local += (cand[i] > my);
    #pragma unroll
    for (int off = 32; off; off >>= 1) local += __shfl_down(local, off);
    if (tid == 0) { sA = 0.0f; sM = 0.0f; }
    if (lane == 0) redI[wid] = local;
    __syncthreads();
    int k = redI[0] + redI[1] + redI[2] + redI[3];
    if (k >= KK) return;

    unsigned pp = 0xFFFFFFFFu - (unsigned)(my & 0xFFFFFFFFull);
    int cy = (int)(pp >> 9), cx = (int)(pp & 511);
    int wy = cy < WSR ? WSR : (cy > HH - WSR ? HH - WSR : cy);
    int wx = cx < WSR ? WSR : (cx > WWI - WSR ? WWI - WSR : cx);
    int gy0 = wy - WSR, gx0 = wx - WSR;
    if (tid == 0) { iy0[k] = gy0; ix0[k] = gx0; }

    float w0 = wc[0], w1 = wc[1], w2 = wc[2], w3 = wc[3], b = bc[0];
    float cyf = (float)cy, cxf = (float)cx;
    const float* x0 = x;
    const float* x1 = x + HWN;
    const float* x2 = x + 2 * HWN;
    const float* x3 = x + 3 * HWN;
    const float* x4 = x + 4 * HWN;
    unsigned long long idbits = (unsigned long long)(unsigned)(k + 1);
    float aA = 0.0f, aM = 0.0f;
    #pragma unroll 4
    for (int q = 0; q < 16; ++q) {
        int p = (q << 8) + tid;
        int row = p >> 6;              // uniform per wave
        int col = p & 63;              // = lane
        int gy = gy0 + row, gx = gx0 + col;
        int g = gy * WWI + gx;
        float gyf = (float)gy;
        float d0 = __fsub_rn(__fadd_rn(x0[g], gyf), cyf);
        float d1 = __fsub_rn(__fadd_rn(x1[g], (float)gx), cxf);
        float s0v = x2[g], s1v = x3[g];
        float t = __fadd_rn(
                    __fadd_rn(
                      __fadd_rn(
                        __fadd_rn(__fmul_rn(w0, d0), __fmul_rn(w1, d1)),
                        __fmul_rn(w2, s0v)),
                      __fmul_rn(w3, s1v)),
                    b);
        float pr = sigm(t);
        probs[k * 4096 + p] = pr;
        bool pass = pr > 0.53f;
        unsigned long long bal = __ballot(pass);
        if (lane == 0) bits[k * 64 + row] = bal;
        if (pass) {
            aA += 1.0f;
            aM += sigm(x4[g]);
            atomicMax(&packed[g],
                      ((unsigned long long)__float_as_uint(pr) << 32) | idbits);
        }
    }
    #pragma unroll
    for (int off = 32; off; off >>= 1) {
        aA += __shfl_down(aA, off);
        aM += __shfl_down(aM, off);
    }
    if (lane == 0) { atomicAdd(&sA, aA); atomicAdd(&sM, aM); }
    __syncthreads();
    if (tid == 0) { areas[k] = sA; msum[k] = sM; }
}

// Pairwise IoU adjacency; the LAST finisher block additionally runs the
// (tiny) connected-components + filter, writing fmap.
__global__ __launch_bounds__(256) void k_pairscc(
        const unsigned long long* __restrict__ cand,
        const unsigned long long* __restrict__ bits,
        const float* __restrict__ areas, const float* __restrict__ msum,
        const int* __restrict__ iy0, const int* __restrict__ ix0,
        unsigned long long* __restrict__ adj, int* __restrict__ done,
        int* __restrict__ fmap) {
    int a = blockIdx.x, tid = threadIdx.x;
    __shared__ unsigned long long rowA[64];
    __shared__ int say0, sax0, islast;
    if (tid < 64) rowA[tid] = bits[a * 64 + tid];
    if (tid == 0) { say0 = iy0[a]; sax0 = ix0[a]; }
    __syncthreads();
    {
        int b2 = tid;
        int ay0 = say0, ax0 = sax0;
        int by0 = iy0[b2], bx0 = ix0[b2];
        int yl = max(ay0, by0), yh = min(ay0 + SSW, by0 + SSW);
        int xl = max(ax0, bx0), xh = min(ax0 + SSW, bx0 + SSW);
        int inter = 0;
        if (yl < yh && xl < xh) {
            int wdt = xh - xl;
            unsigned long long cmask = (wdt >= 64) ? ~0ull : ((1ull << wdt) - 1ull);
            int sa = xl - ax0, sb = xl - bx0;
            for (int y = yl; y < yh; ++y) {
                unsigned long long wa = rowA[y - ay0] >> sa;
                unsigned long long wb = bits[b2 * 64 + (y - by0)] >> sb;
                inter += __popcll(wa & wb & cmask);
            }
        }
        float fi = (float)inter;
        float uni = __fsub_rn(__fadd_rn(areas[a], areas[b2]), fi);
        bool adjb = (fi / fmaxf(uni, 1.0f)) > 0.3f;
        unsigned long long bal = __ballot(adjb);
        if ((tid & 63) == 0) adj[a * 4 + (tid >> 6)] = bal;
    }
    __threadfence();
    __syncthreads();
    if (tid == 0) islast = (atomicAdd(done, 1) == KK - 1);
    __syncthreads();
    if (!islast) return;
    __threadfence();   // acquire: all blocks' adj now visible

    __shared__ unsigned long long adjS[KK][4];
    __shared__ int lbl[KK];
    __shared__ unsigned char rem[KK];
    __shared__ int changed, redI[4];
    int lane = tid & 63, wid = tid >> 6;
    int local = 0;
    for (int i = tid; i < CAND_CAP; i += 256) local += (cand[i] != 0ull);
    #pragma unroll
    for (int off = 32; off; off >>= 1) local += __shfl_down(local, off);
    if (lane == 0) redI[wid] = local;
    for (int w = 0; w < 4; ++w) adjS[tid][w] = adj[tid * 4 + w];
    lbl[tid] = tid;
    __syncthreads();
    int cnt = redI[0] + redI[1] + redI[2] + redI[3];
    for (int it = 0; it < 32; ++it) {
        int m = KK;
        for (int w = 0; w < 4; ++w) {
            unsigned long long bb = adjS[tid][w];
            while (bb) {
                int j = __ffsll((unsigned long long)bb) - 1;
                int v = lbl[(w << 6) | j];
                m = v < m ? v : m;
                bb &= bb - 1;
            }
        }
        if (tid == 0) changed = 0;
        __syncthreads();
        if (m != lbl[tid]) { lbl[tid] = m; atomicOr(&changed, 1); }
        __syncthreads();
        if (!changed) break;
    }
    float area = areas[tid];
    bool validf = tid < cnt;
    float mean = msum[tid] / fmaxf(area, 1.0f);
    rem[tid] = (unsigned char)(!((mean > 0.0f) && (area > 10.0f) && validf));
    __syncthreads();
    int root = lbl[tid];
    int rc = root < 255 ? root : 255;
    fmap[tid] = rem[rc] ? 0 : (root + 1);
}

__global__ void k_final(const unsigned long long* __restrict__ packed,
                        const int* __restrict__ fmap, float* __restrict__ labels) {
    int p = blockIdx.x * blockDim.x + threadIdx.x;
    if (p < HWN) {
        unsigned l = (unsigned)(packed[p] & 0xFFFFFFFFull);
        labels[p] = l ? (float)fmap[l - 1] : 0.0f;
    }
}

extern "C" void kernel_launch(void* const* d_in, const int* in_sizes, int n_in,
                              void* d_out, int out_size, void* d_ws, size_t ws_size,
                              hipStream_t stream) {
    const float* x  = (const float*)d_in[0];
    const float* wc = (const float*)d_in[1];
    const float* bc = (const float*)d_in[2];
    float* labels = (float*)d_out;
    float* probs  = (float*)d_out + HWN;

    char* ws = (char*)d_ws;
    unsigned long long* packed  = (unsigned long long*)(ws + OFF_PACKED);
    unsigned long long* bits    = (unsigned long long*)(ws + OFF_BITS);
    float*              areas   = (float*)(ws + OFF_AREA);
    float*              msum    = (float*)(ws + OFF_MSUM);
    int*                iy0p    = (int*)(ws + OFF_WY0);
    int*                ix0p    = (int*)(ws + OFF_WX0);
    int*                fmap    = (int*)(ws + OFF_FINAL);
    int*                done    = (int*)(ws + OFF_DONE);
    unsigned long long* adj     = (unsigned long long*)(ws + OFF_ADJ);
    unsigned long long* cand    = (unsigned long long*)(ws + OFF_CAND);

    k_front  <<<256, 256, 0, stream>>>(x + 4 * HWN, cand, packed, bits,
                                       areas, msum, iy0p, ix0p, done);
    k_win2   <<<CAND_CAP + KK, 256, 0, stream>>>(x, wc, bc, cand, probs, packed,
                                                 bits, areas, msum, iy0p, ix0p);
    k_pairscc<<<KK, 256, 0, stream>>>(cand, bits, areas, msum, iy0p, ix0p,
                                      adj, done, fmap);
    k_final  <<<HWN / 256, 256, 0, stream>>>(packed, fmap, labels);
}

// Round 10
// 66.576 us; speedup vs baseline: 3.5841x; 1.1775x over previous
//
#include <hip/hip_runtime.h>
#include <stdint.h>

#define HH   512
#define WWI  512
#define HWN  (HH*WWI)
#define KK   256
#define WSR  32
#define SSW  64
#define RPB  4                         // rows per front strip block
#define HALO 5
#define SROWS (RPB + 2*HALO)           // 14
#define NFRONT 128                     // HH/RPB
#define CPB  32                        // candidate slots per strip
#define CAND_CAP 4096                  // NFRONT*CPB

// workspace byte offsets
#define OFF_PACKED 0u                  // HWN*8 = 2 MB   (pr_bits<<32 | winner_id)
#define OFF_BITS   2097152u            // 256*64*8 = 128 KB
#define OFF_AREA   2228224u            // 1 KB
#define OFF_MSUM   2229248u            // 1 KB
#define OFF_WY0    2230272u            // 1 KB
#define OFF_WX0    2231296u            // 1 KB
#define OFF_FINAL  2232320u            // 1 KB
#define OFF_ADJ    2233352u            // 8 KB
#define OFF_CAND   2241544u            // 32 KB

__device__ __forceinline__ float sigm(float v) {
    return 1.0f / (1.0f + expf(-v));
}

// Front: blocks [0,128) = sigmoid + separable 11x11 max + peak emit (private
// candidate regions). Blocks [128,256) = all zero-fills (run concurrently).
__global__ __launch_bounds__(256) void k_front(const float* __restrict__ x4,
        unsigned long long* __restrict__ cand,
        unsigned long long* __restrict__ packed,
        unsigned long long* __restrict__ bits,
        float* __restrict__ areas, float* __restrict__ msum,
        int* __restrict__ iy0, int* __restrict__ ix0) {
    int tid = threadIdx.x, bid = blockIdx.x;
    if (bid < NFRONT) {
        __shared__ float vm[RPB][WWI];
        __shared__ int lcnt;
        int r0 = bid * RPB;
        if (tid == 0) lcnt = 0;
        if (tid < CPB) cand[bid * CPB + tid] = 0ull;
        float s0[SROWS], s1[SROWS];
        #pragma unroll
        for (int hr = 0; hr < SROWS; ++hr) {
            int gr = r0 - HALO + hr; gr = gr < 0 ? 0 : (gr > HH-1 ? HH-1 : gr);
            const float* row = x4 + gr * WWI;
            s0[hr] = sigm(row[tid]);
            s1[hr] = sigm(row[tid + 256]);
        }
        #pragma unroll
        for (int rr = 0; rr < RPB; ++rr) {
            float a = s0[rr], b = s1[rr];
            #pragma unroll
            for (int d = 1; d < 11; ++d) { a = fmaxf(a, s0[rr+d]); b = fmaxf(b, s1[rr+d]); }
            vm[rr][tid] = a; vm[rr][tid + 256] = b;
        }
        __syncthreads();
        #pragma unroll
        for (int rr = 0; rr < RPB; ++rr) {
            int gy = r0 + rr;
            {
                int c = tid;
                float m = s0[rr + HALO];
                if (m > 0.7f) {
                    int c0 = c-5 < 0 ? 0 : c-5, c1 = c+5;
                    float v = -1.0f;
                    for (int cc = c0; cc <= c1; ++cc) v = fmaxf(v, vm[rr][cc]);
                    if (m == v) {
                        int slot = atomicAdd(&lcnt, 1);
                        if (slot < CPB) {
                            unsigned p = (unsigned)(gy * WWI + c);
                            cand[bid * CPB + slot] =
                                ((unsigned long long)__float_as_uint(m) << 32) |
                                (unsigned long long)(0xFFFFFFFFu - p);
                        }
                    }
                }
            }
            {
                int c = tid + 256;
                float m = s1[rr + HALO];
                if (m > 0.7f) {
                    int c0 = c-5, c1 = c+5 > 511 ? 511 : c+5;
                    float v = -1.0f;
                    for (int cc = c0; cc <= c1; ++cc) v = fmaxf(v, vm[rr][cc]);
                    if (m == v) {
                        int slot = atomicAdd(&lcnt, 1);
                        if (slot < CPB) {
                            unsigned p = (unsigned)(gy * WWI + c);
                            cand[bid * CPB + slot] =
                                ((unsigned long long)__float_as_uint(m) << 32) |
                                (unsigned long long)(0xFFFFFFFFu - p);
                        }
                    }
                }
            }
        }
    } else {
        int gt = (bid - NFRONT) * 256 + tid;       // [0, 32768)
        // packed: 262144 u64 -> 8 contiguous u64 (64 B) per thread, vectorized
        ulonglong2 z; z.x = 0ull; z.y = 0ull;
        ulonglong2* p2 = (ulonglong2*)(packed + (size_t)gt * 8);
        p2[0] = z; p2[1] = z; p2[2] = z; p2[3] = z;
        if (gt < KK * 64) bits[gt] = 0ull;
        if (gt < KK) { areas[gt] = 0.0f; msum[gt] = 0.0f; iy0[gt] = 0; ix0[gt] = 0; }
    }
}

// Windowed classifier per candidate. Block derives its candidate's global
// descending-sort rank by scanning all keys (L2-resident), then computes the
// 64x64 window: coalesced loads, probs store, ballot row-bitmaps, and ONE
// packed 64-bit atomicMax (pr_bits<<32 | id) = winner labeling fused in.
// Tail blocks zero probs for unfilled rank slots.
__global__ __launch_bounds__(256) void k_win2(const float* __restrict__ x,
        const float* __restrict__ wc, const float* __restrict__ bc,
        const unsigned long long* __restrict__ cand,
        float* __restrict__ probs, unsigned long long* __restrict__ packed,
        unsigned long long* __restrict__ bits,
        float* __restrict__ areas, float* __restrict__ msum,
        int* __restrict__ iy0, int* __restrict__ ix0) {
    int bid = blockIdx.x, tid = threadIdx.x;
    int lane = tid & 63, wid = tid >> 6;
    __shared__ int redI[4];
    __shared__ float sA, sM;
    if (bid >= CAND_CAP) {             // tail: zero unfilled prob slots
        int j = bid - CAND_CAP;
        int local = 0;
        for (int i = tid; i < CAND_CAP; i += 256) local += (cand[i] != 0ull);
        #pragma unroll
        for (int off = 32; off; off >>= 1) local += __shfl_down(local, off);
        if (lane == 0) redI[wid] = local;
        __syncthreads();
        int cnt = redI[0] + redI[1] + redI[2] + redI[3];
        if (cnt > KK) cnt = KK;
        if (j >= cnt) for (int i = tid; i < 4096; i += 256) probs[j * 4096 + i] = 0.0f;
        return;
    }
    unsigned long long my = cand[bid];
    if (my == 0ull) return;
    int local = 0;
    for (int i = tid; i < CAND_CAP; i += 256) local += (cand[i] > my);
    #pragma unroll
    for (int off = 32; off; off >>= 1) local += __shfl_down(local, off);
    if (tid == 0) { sA = 0.0f; sM = 0.0f; }
    if (lane == 0) redI[wid] = local;
    __syncthreads();
    int k = redI[0] + redI[1] + redI[2] + redI[3];
    if (k >= KK) return;

    unsigned pp = 0xFFFFFFFFu - (unsigned)(my & 0xFFFFFFFFull);
    int cy = (int)(pp >> 9), cx = (int)(pp & 511);
    int wy = cy < WSR ? WSR : (cy > HH - WSR ? HH - WSR : cy);
    int wx = cx < WSR ? WSR : (cx > WWI - WSR ? WWI - WSR : cx);
    int gy0 = wy - WSR, gx0 = wx - WSR;
    if (tid == 0) { iy0[k] = gy0; ix0[k] = gx0; }

    float w0 = wc[0], w1 = wc[1], w2 = wc[2], w3 = wc[3], b = bc[0];
    float cyf = (float)cy, cxf = (float)cx;
    const float* x0 = x;
    const float* x1 = x + HWN;
    const float* x2 = x + 2 * HWN;
    const float* x3 = x + 3 * HWN;
    const float* x4 = x + 4 * HWN;
    unsigned long long idbits = (unsigned long long)(unsigned)(k + 1);
    float aA = 0.0f, aM = 0.0f;
    #pragma unroll 4
    for (int q = 0; q < 16; ++q) {
        int p = (q << 8) + tid;
        int row = p >> 6;              // uniform per wave
        int col = p & 63;              // = lane
        int gy = gy0 + row, gx = gx0 + col;
        int g = gy * WWI + gx;
        float gyf = (float)gy;
        float d0 = __fsub_rn(__fadd_rn(x0[g], gyf), cyf);
        float d1 = __fsub_rn(__fadd_rn(x1[g], (float)gx), cxf);
        float s0v = x2[g], s1v = x3[g];
        float t = __fadd_rn(
                    __fadd_rn(
                      __fadd_rn(
                        __fadd_rn(__fmul_rn(w0, d0), __fmul_rn(w1, d1)),
                        __fmul_rn(w2, s0v)),
                      __fmul_rn(w3, s1v)),
                    b);
        float pr = sigm(t);
        probs[k * 4096 + p] = pr;
        bool pass = pr > 0.53f;
        unsigned long long bal = __ballot(pass);
        if (lane == 0) bits[k * 64 + row] = bal;
        if (pass) {
            aA += 1.0f;
            aM += sigm(x4[g]);
            atomicMax(&packed[g],
                      ((unsigned long long)__float_as_uint(pr) << 32) | idbits);
        }
    }
    #pragma unroll
    for (int off = 32; off; off >>= 1) {
        aA += __shfl_down(aA, off);
        aM += __shfl_down(aM, off);
    }
    if (lane == 0) { atomicAdd(&sA, aA); atomicAdd(&sM, aM); }
    __syncthreads();
    if (tid == 0) { areas[k] = sA; msum[k] = sM; }
}

// Pairwise IoU adjacency (fence-free).
__global__ __launch_bounds__(256) void k_pairs(
        const unsigned long long* __restrict__ bits,
        const float* __restrict__ areas,
        const int* __restrict__ iy0, const int* __restrict__ ix0,
        unsigned long long* __restrict__ adj) {
    int a = blockIdx.x, tid = threadIdx.x;
    __shared__ unsigned long long rowA[64];
    __shared__ int say0, sax0;
    if (tid < 64) rowA[tid] = bits[a * 64 + tid];
    if (tid == 0) { say0 = iy0[a]; sax0 = ix0[a]; }
    __syncthreads();
    int b2 = tid;
    int ay0 = say0, ax0 = sax0;
    int by0 = iy0[b2], bx0 = ix0[b2];
    int yl = max(ay0, by0), yh = min(ay0 + SSW, by0 + SSW);
    int xl = max(ax0, bx0), xh = min(ax0 + SSW, bx0 + SSW);
    int inter = 0;
    if (yl < yh && xl < xh) {
        int wdt = xh - xl;
        unsigned long long cmask = (wdt >= 64) ? ~0ull : ((1ull << wdt) - 1ull);
        int sa = xl - ax0, sb = xl - bx0;
        for (int y = yl; y < yh; ++y) {
            unsigned long long wa = rowA[y - ay0] >> sa;
            unsigned long long wb = bits[b2 * 64 + (y - by0)] >> sb;
            inter += __popcll(wa & wb & cmask);
        }
    }
    float fi = (float)inter;
    float uni = __fsub_rn(__fadd_rn(areas[a], areas[b2]), fi);
    bool adjb = (fi / fmaxf(uni, 1.0f)) > 0.3f;
    unsigned long long bal = __ballot(adjb);
    if ((tid & 63) == 0) adj[a * 4 + (tid >> 6)] = bal;
}

// Connected components + filter (1 block).
__global__ __launch_bounds__(256) void k_cc(
        const unsigned long long* __restrict__ cand,
        const unsigned long long* __restrict__ adj,
        const float* __restrict__ areas, const float* __restrict__ msum,
        int* __restrict__ fmap) {
    __shared__ unsigned long long adjS[KK][4];
    __shared__ int lbl[KK];
    __shared__ unsigned char rem[KK];
    __shared__ int changed, redI[4];
    int tid = threadIdx.x;
    int lane = tid & 63, wid = tid >> 6;
    int local = 0;
    for (int i = tid; i < CAND_CAP; i += 256) local += (cand[i] != 0ull);
    #pragma unroll
    for (int off = 32; off; off >>= 1) local += __shfl_down(local, off);
    if (lane == 0) redI[wid] = local;
    for (int w = 0; w < 4; ++w) adjS[tid][w] = adj[tid * 4 + w];
    lbl[tid] = tid;
    __syncthreads();
    int cnt = redI[0] + redI[1] + redI[2] + redI[3];
    for (int it = 0; it < 32; ++it) {
        int m = KK;
        for (int w = 0; w < 4; ++w) {
            unsigned long long bb = adjS[tid][w];
            while (bb) {
                int j = __ffsll((unsigned long long)bb) - 1;
                int v = lbl[(w << 6) | j];
                m = v < m ? v : m;
                bb &= bb - 1;
            }
        }
        if (tid == 0) changed = 0;
        __syncthreads();
        if (m != lbl[tid]) { lbl[tid] = m; atomicOr(&changed, 1); }
        __syncthreads();
        if (!changed) break;
    }
    float area = areas[tid];
    bool validf = tid < cnt;
    float mean = msum[tid] / fmaxf(area, 1.0f);
    rem[tid] = (unsigned char)(!((mean > 0.0f) && (area > 10.0f) && validf));
    __syncthreads();
    int root = lbl[tid];
    int rc = root < 255 ? root : 255;
    fmap[tid] = rem[rc] ? 0 : (root + 1);
}

// Final relabel, 4 pixels/thread, vectorized.
__global__ __launch_bounds__(256) void k_final(
        const unsigned long long* __restrict__ packed,
        const int* __restrict__ fmap, float* __restrict__ labels) {
    int i = blockIdx.x * 256 + threadIdx.x;          // [0, 65536)
    const ulonglong2* p2 = (const ulonglong2*)(packed + (size_t)i * 4);
    ulonglong2 a = p2[0], b = p2[1];
    float4 o;
    unsigned l0 = (unsigned)(a.x & 0xFFFFFFFFull);
    unsigned l1 = (unsigned)(a.y & 0xFFFFFFFFull);
    unsigned l2 = (unsigned)(b.x & 0xFFFFFFFFull);
    unsigned l3 = (unsigned)(b.y & 0xFFFFFFFFull);
    o.x = l0 ? (float)fmap[l0 - 1] : 0.0f;
    o.y = l1 ? (float)fmap[l1 - 1] : 0.0f;
    o.z = l2 ? (float)fmap[l2 - 1] : 0.0f;
    o.w = l3 ? (float)fmap[l3 - 1] : 0.0f;
    *(float4*)(labels + (size_t)i * 4) = o;
}

extern "C" void kernel_launch(void* const* d_in, const int* in_sizes, int n_in,
                              void* d_out, int out_size, void* d_ws, size_t ws_size,
                              hipStream_t stream) {
    const float* x  = (const float*)d_in[0];
    const float* wc = (const float*)d_in[1];
    const float* bc = (const float*)d_in[2];
    float* labels = (float*)d_out;
    float* probs  = (float*)d_out + HWN;

    char* ws = (char*)d_ws;
    unsigned long long* packed  = (unsigned long long*)(ws + OFF_PACKED);
    unsigned long long* bits    = (unsigned long long*)(ws + OFF_BITS);
    float*              areas   = (float*)(ws + OFF_AREA);
    float*              msum    = (float*)(ws + OFF_MSUM);
    int*                iy0p    = (int*)(ws + OFF_WY0);
    int*                ix0p    = (int*)(ws + OFF_WX0);
    int*                fmap    = (int*)(ws + OFF_FINAL);
    unsigned long long* adj     = (unsigned long long*)(ws + OFF_ADJ);
    unsigned long long* cand    = (unsigned long long*)(ws + OFF_CAND);

    k_front<<<256, 256, 0, stream>>>(x + 4 * HWN, cand, packed, bits,
                                     areas, msum, iy0p, ix0p);
    k_win2 <<<CAND_CAP + KK, 256, 0, stream>>>(x, wc, bc, cand, probs, packed,
                                               bits, areas, msum, iy0p, ix0p);
    k_pairs<<<KK, 256, 0, stream>>>(bits, areas, iy0p, ix0p, adj);
    k_cc   <<<1, 256, 0, stream>>>(cand, adj, areas, msum, fmap);
    k_final<<<HWN / 1024, 256, 0, stream>>>(packed, fmap, labels);
}

// Round 11
// 65.164 us; speedup vs baseline: 3.6617x; 1.0217x over previous
//
#include <hip/hip_runtime.h>
#include <stdint.h>

#define HH   512
#define WWI  512
#define HWN  (HH*WWI)
#define KK   256
#define WSR  32
#define SSW  64
#define RPB  4                         // rows per front strip block
#define HALO 5
#define SROWS (RPB + 2*HALO)           // 14
#define NFRONT 128                     // HH/RPB
#define CPB  32                        // candidate slots per strip
#define CAND_CAP 4096                  // NFRONT*CPB

// workspace byte offsets
#define OFF_PACKED 0u                  // HWN*8 = 2 MB   (pr_bits<<32 | winner_id)
#define OFF_BITS   2097152u            // 256*64*8 = 128 KB
#define OFF_AREA   2228224u            // 1 KB
#define OFF_MSUM   2229248u            // 1 KB
#define OFF_WY0    2230272u            // 1 KB
#define OFF_WX0    2231296u            // 1 KB
#define OFF_ADJ    2233352u            // 8 KB
#define OFF_CAND   2241544u            // 32 KB

__device__ __forceinline__ float sigm(float v) {
    return 1.0f / (1.0f + expf(-v));
}

// Front: blocks [0,128) = sigmoid + separable 11x11 max + peak emit (private
// candidate regions). Blocks [128,256) = all zero-fills (run concurrently).
__global__ __launch_bounds__(256) void k_front(const float* __restrict__ x4,
        unsigned long long* __restrict__ cand,
        unsigned long long* __restrict__ packed,
        unsigned long long* __restrict__ bits,
        float* __restrict__ areas, float* __restrict__ msum,
        int* __restrict__ iy0, int* __restrict__ ix0) {
    int tid = threadIdx.x, bid = blockIdx.x;
    if (bid < NFRONT) {
        __shared__ float vm[RPB][WWI];
        __shared__ int lcnt;
        int r0 = bid * RPB;
        if (tid == 0) lcnt = 0;
        if (tid < CPB) cand[bid * CPB + tid] = 0ull;
        float s0[SROWS], s1[SROWS];
        #pragma unroll
        for (int hr = 0; hr < SROWS; ++hr) {
            int gr = r0 - HALO + hr; gr = gr < 0 ? 0 : (gr > HH-1 ? HH-1 : gr);
            const float* row = x4 + gr * WWI;
            s0[hr] = sigm(row[tid]);
            s1[hr] = sigm(row[tid + 256]);
        }
        #pragma unroll
        for (int rr = 0; rr < RPB; ++rr) {
            float a = s0[rr], b = s1[rr];
            #pragma unroll
            for (int d = 1; d < 11; ++d) { a = fmaxf(a, s0[rr+d]); b = fmaxf(b, s1[rr+d]); }
            vm[rr][tid] = a; vm[rr][tid + 256] = b;
        }
        __syncthreads();
        #pragma unroll
        for (int rr = 0; rr < RPB; ++rr) {
            int gy = r0 + rr;
            {
                int c = tid;
                float m = s0[rr + HALO];
                if (m > 0.7f) {
                    int c0 = c-5 < 0 ? 0 : c-5, c1 = c+5;
                    float v = -1.0f;
                    for (int cc = c0; cc <= c1; ++cc) v = fmaxf(v, vm[rr][cc]);
                    if (m == v) {
                        int slot = atomicAdd(&lcnt, 1);
                        if (slot < CPB) {
                            unsigned p = (unsigned)(gy * WWI + c);
                            cand[bid * CPB + slot] =
                                ((unsigned long long)__float_as_uint(m) << 32) |
                                (unsigned long long)(0xFFFFFFFFu - p);
                        }
                    }
                }
            }
            {
                int c = tid + 256;
                float m = s1[rr + HALO];
                if (m > 0.7f) {
                    int c0 = c-5, c1 = c+5 > 511 ? 511 : c+5;
                    float v = -1.0f;
                    for (int cc = c0; cc <= c1; ++cc) v = fmaxf(v, vm[rr][cc]);
                    if (m == v) {
                        int slot = atomicAdd(&lcnt, 1);
                        if (slot < CPB) {
                            unsigned p = (unsigned)(gy * WWI + c);
                            cand[bid * CPB + slot] =
                                ((unsigned long long)__float_as_uint(m) << 32) |
                                (unsigned long long)(0xFFFFFFFFu - p);
                        }
                    }
                }
            }
        }
    } else {
        int gt = (bid - NFRONT) * 256 + tid;       // [0, 32768)
        // packed: 262144 u64 -> 8 contiguous u64 (64 B) per thread, vectorized
        ulonglong2 z; z.x = 0ull; z.y = 0ull;
        ulonglong2* p2 = (ulonglong2*)(packed + (size_t)gt * 8);
        p2[0] = z; p2[1] = z; p2[2] = z; p2[3] = z;
        if (gt < KK * 64) bits[gt] = 0ull;
        if (gt < KK) { areas[gt] = 0.0f; msum[gt] = 0.0f; iy0[gt] = 0; ix0[gt] = 0; }
    }
}

// Windowed classifier per candidate. Block derives its candidate's global
// descending-sort rank by scanning all keys (L2-resident), then computes the
// 64x64 window: coalesced loads, probs store, ballot row-bitmaps, and ONE
// packed 64-bit atomicMax (pr_bits<<32 | id) = winner labeling fused in.
// Tail blocks zero probs for unfilled rank slots.
__global__ __launch_bounds__(256) void k_win2(const float* __restrict__ x,
        const float* __restrict__ wc, const float* __restrict__ bc,
        const unsigned long long* __restrict__ cand,
        float* __restrict__ probs, unsigned long long* __restrict__ packed,
        unsigned long long* __restrict__ bits,
        float* __restrict__ areas, float* __restrict__ msum,
        int* __restrict__ iy0, int* __restrict__ ix0) {
    int bid = blockIdx.x, tid = threadIdx.x;
    int lane = tid & 63, wid = tid >> 6;
    __shared__ int redI[4];
    __shared__ float sA, sM;
    if (bid >= CAND_CAP) {             // tail: zero unfilled prob slots
        int j = bid - CAND_CAP;
        int local = 0;
        for (int i = tid; i < CAND_CAP; i += 256) local += (cand[i] != 0ull);
        #pragma unroll
        for (int off = 32; off; off >>= 1) local += __shfl_down(local, off);
        if (lane == 0) redI[wid] = local;
        __syncthreads();
        int cnt = redI[0] + redI[1] + redI[2] + redI[3];
        if (cnt > KK) cnt = KK;
        if (j >= cnt) for (int i = tid; i < 4096; i += 256) probs[j * 4096 + i] = 0.0f;
        return;
    }
    unsigned long long my = cand[bid];
    if (my == 0ull) return;
    int local = 0;
    for (int i = tid; i < CAND_CAP; i += 256) local += (cand[i] > my);
    #pragma unroll
    for (int off = 32; off; off >>= 1) local += __shfl_down(local, off);
    if (tid == 0) { sA = 0.0f; sM = 0.0f; }
    if (lane == 0) redI[wid] = local;
    __syncthreads();
    int k = redI[0] + redI[1] + redI[2] + redI[3];
    if (k >= KK) return;

    unsigned pp = 0xFFFFFFFFu - (unsigned)(my & 0xFFFFFFFFull);
    int cy = (int)(pp >> 9), cx = (int)(pp & 511);
    int wy = cy < WSR ? WSR : (cy > HH - WSR ? HH - WSR : cy);
    int wx = cx < WSR ? WSR : (cx > WWI - WSR ? WWI - WSR : cx);
    int gy0 = wy - WSR, gx0 = wx - WSR;
    if (tid == 0) { iy0[k] = gy0; ix0[k] = gx0; }

    float w0 = wc[0], w1 = wc[1], w2 = wc[2], w3 = wc[3], b = bc[0];
    float cyf = (float)cy, cxf = (float)cx;
    const float* x0 = x;
    const float* x1 = x + HWN;
    const float* x2 = x + 2 * HWN;
    const float* x3 = x + 3 * HWN;
    const float* x4 = x + 4 * HWN;
    unsigned long long idbits = (unsigned long long)(unsigned)(k + 1);
    float aA = 0.0f, aM = 0.0f;
    #pragma unroll 4
    for (int q = 0; q < 16; ++q) {
        int p = (q << 8) + tid;
        int row = p >> 6;              // uniform per wave
        int col = p & 63;              // = lane
        int gy = gy0 + row, gx = gx0 + col;
        int g = gy * WWI + gx;
        float gyf = (float)gy;
        float d0 = __fsub_rn(__fadd_rn(x0[g], gyf), cyf);
        float d1 = __fsub_rn(__fadd_rn(x1[g], (float)gx), cxf);
        float s0v = x2[g], s1v = x3[g];
        float t = __fadd_rn(
                    __fadd_rn(
                      __fadd_rn(
                        __fadd_rn(__fmul_rn(w0, d0), __fmul_rn(w1, d1)),
                        __fmul_rn(w2, s0v)),
                      __fmul_rn(w3, s1v)),
                    b);
        float pr = sigm(t);
        probs[k * 4096 + p] = pr;
        bool pass = pr > 0.53f;
        unsigned long long bal = __ballot(pass);
        if (lane == 0) bits[k * 64 + row] = bal;
        if (pass) {
            aA += 1.0f;
            aM += sigm(x4[g]);
            atomicMax(&packed[g],
                      ((unsigned long long)__float_as_uint(pr) << 32) | idbits);
        }
    }
    #pragma unroll
    for (int off = 32; off; off >>= 1) {
        aA += __shfl_down(aA, off);
        aM += __shfl_down(aM, off);
    }
    if (lane == 0) { atomicAdd(&sA, aA); atomicAdd(&sM, aM); }
    __syncthreads();
    if (tid == 0) { areas[k] = sA; msum[k] = sM; }
}

// Pairwise IoU adjacency (fence-free).
__global__ __launch_bounds__(256) void k_pairs(
        const unsigned long long* __restrict__ bits,
        const float* __restrict__ areas,
        const int* __restrict__ iy0, const int* __restrict__ ix0,
        unsigned long long* __restrict__ adj) {
    int a = blockIdx.x, tid = threadIdx.x;
    __shared__ unsigned long long rowA[64];
    __shared__ int say0, sax0;
    if (tid < 64) rowA[tid] = bits[a * 64 + tid];
    if (tid == 0) { say0 = iy0[a]; sax0 = ix0[a]; }
    __syncthreads();
    int b2 = tid;
    int ay0 = say0, ax0 = sax0;
    int by0 = iy0[b2], bx0 = ix0[b2];
    int yl = max(ay0, by0), yh = min(ay0 + SSW, by0 + SSW);
    int xl = max(ax0, bx0), xh = min(ax0 + SSW, bx0 + SSW);
    int inter = 0;
    if (yl < yh && xl < xh) {
        int wdt = xh - xl;
        unsigned long long cmask = (wdt >= 64) ? ~0ull : ((1ull << wdt) - 1ull);
        int sa = xl - ax0, sb = xl - bx0;
        for (int y = yl; y < yh; ++y) {
            unsigned long long wa = rowA[y - ay0] >> sa;
            unsigned long long wb = bits[b2 * 64 + (y - by0)] >> sb;
            inter += __popcll(wa & wb & cmask);
        }
    }
    float fi = (float)inter;
    float uni = __fsub_rn(__fadd_rn(areas[a], areas[b2]), fi);
    bool adjb = (fi / fmaxf(uni, 1.0f)) > 0.3f;
    unsigned long long bal = __ballot(adjb);
    if ((tid & 63) == 0) adj[a * 4 + (tid >> 6)] = bal;
}

// Final: every block redundantly computes CC+filter in LDS (identical result,
// deterministic; adj/areas/msum visible via kernel boundary), then relabels
// its 1024 pixels (4 px/thread, vectorized). No fence, no extra dispatch.
__global__ __launch_bounds__(256) void k_final(
        const unsigned long long* __restrict__ packed,
        const unsigned long long* __restrict__ cand,
        const unsigned long long* __restrict__ adj,
        const float* __restrict__ areas, const float* __restrict__ msum,
        float* __restrict__ labels) {
    __shared__ unsigned long long adjS[KK][4];
    __shared__ int lbl[KK];
    __shared__ int fmS[KK];
    __shared__ unsigned char rem[KK];
    __shared__ int changed, redI[4];
    int tid = threadIdx.x;
    int lane = tid & 63, wid = tid >> 6;
    int local = 0;
    for (int i = tid; i < CAND_CAP; i += 256) local += (cand[i] != 0ull);
    #pragma unroll
    for (int off = 32; off; off >>= 1) local += __shfl_down(local, off);
    if (lane == 0) redI[wid] = local;
    for (int w = 0; w < 4; ++w) adjS[tid][w] = adj[tid * 4 + w];
    lbl[tid] = tid;
    __syncthreads();
    int cnt = redI[0] + redI[1] + redI[2] + redI[3];
    for (int it = 0; it < 32; ++it) {
        int m = KK;
        for (int w = 0; w < 4; ++w) {
            unsigned long long bb = adjS[tid][w];
            while (bb) {
                int j = __ffsll((unsigned long long)bb) - 1;
                int v = lbl[(w << 6) | j];
                m = v < m ? v : m;
                bb &= bb - 1;
            }
        }
        if (tid == 0) changed = 0;
        __syncthreads();
        if (m != lbl[tid]) { lbl[tid] = m; atomicOr(&changed, 1); }
        __syncthreads();
        if (!changed) break;
    }
    float area = areas[tid];
    bool validf = tid < cnt;
    float mean = msum[tid] / fmaxf(area, 1.0f);
    rem[tid] = (unsigned char)(!((mean > 0.0f) && (area > 10.0f) && validf));
    __syncthreads();
    {
        int root = lbl[tid];
        int rc = root < 255 ? root : 255;
        fmS[tid] = rem[rc] ? 0 : (root + 1);
    }
    __syncthreads();

    int i = blockIdx.x * 256 + tid;                 // [0, 65536)
    const ulonglong2* p2 = (const ulonglong2*)(packed + (size_t)i * 4);
    ulonglong2 a = p2[0], b = p2[1];
    float4 o;
    unsigned l0 = (unsigned)(a.x & 0xFFFFFFFFull);
    unsigned l1 = (unsigned)(a.y & 0xFFFFFFFFull);
    unsigned l2 = (unsigned)(b.x & 0xFFFFFFFFull);
    unsigned l3 = (unsigned)(b.y & 0xFFFFFFFFull);
    o.x = l0 ? (float)fmS[l0 - 1] : 0.0f;
    o.y = l1 ? (float)fmS[l1 - 1] : 0.0f;
    o.z = l2 ? (float)fmS[l2 - 1] : 0.0f;
    o.w = l3 ? (float)fmS[l3 - 1] : 0.0f;
    *(float4*)(labels + (size_t)i * 4) = o;
}

extern "C" void kernel_launch(void* const* d_in, const int* in_sizes, int n_in,
                              void* d_out, int out_size, void* d_ws, size_t ws_size,
                              hipStream_t stream) {
    const float* x  = (const float*)d_in[0];
    const float* wc = (const float*)d_in[1];
    const float* bc = (const float*)d_in[2];
    float* labels = (float*)d_out;
    float* probs  = (float*)d_out + HWN;

    char* ws = (char*)d_ws;
    unsigned long long* packed  = (unsigned long long*)(ws + OFF_PACKED);
    unsigned long long* bits    = (unsigned long long*)(ws + OFF_BITS);
    float*              areas   = (float*)(ws + OFF_AREA);
    float*              msum    = (float*)(ws + OFF_MSUM);
    int*                iy0p    = (int*)(ws + OFF_WY0);
    int*                ix0p    = (int*)(ws + OFF_WX0);
    unsigned long long* adj     = (unsigned long long*)(ws + OFF_ADJ);
    unsigned long long* cand    = (unsigned long long*)(ws + OFF_CAND);

    k_front<<<256, 256, 0, stream>>>(x + 4 * HWN, cand, packed, bits,
                                     areas, msum, iy0p, ix0p);
    k_win2 <<<CAND_CAP + KK, 256, 0, stream>>>(x, wc, bc, cand, probs, packed,
                                               bits, areas, msum, iy0p, ix0p);
    k_pairs<<<KK, 256, 0, stream>>>(bits, areas, iy0p, ix0p, adj);
    k_final<<<HWN / 1024, 256, 0, stream>>>(packed, cand, adj, areas, msum, labels);
}

// Round 12
// 46.321 us; speedup vs baseline: 5.1513x; 1.4068x over previous
//
#include <hip/hip_runtime.h>
#include <stdint.h>

#define HH   512
#define WWI  512
#define HWN  (HH*WWI)
#define KK   256
#define WSR  32
#define SSW  64
#define RPB  4                         // rows per front strip block
#define HALO 5
#define SROWS (RPB + 2*HALO)           // 14
#define NFRONT 128                     // HH/RPB
#define CPB  32                        // candidate slots per strip
#define CAND_CAP 4096                  // NFRONT*CPB
#define SUB  4                         // window sub-blocks per candidate

// workspace byte offsets
#define OFF_PACKED 0u                  // HWN*8 = 2 MB (pr_bits<<32 | winner_id)
#define OFF_BITSG  2097152u            // 512*256*8 = 1 MB (global-row bitmaps)
#define OFF_AREA   3145728u            // 1 KB
#define OFF_MSUM   3146752u            // 1 KB
#define OFF_WY0    3147776u            // 1 KB
#define OFF_WX0    3148800u            // 1 KB
#define OFF_ADJ    3149824u            // 8 KB
#define OFF_CAND   3158016u            // 32 KB
#define OFF_RANK   3190784u            // 16 KB
#define OFF_CNT    3207168u            // 4 B

__device__ __forceinline__ float sigm(float v) {
    return 1.0f / (1.0f + expf(-v));
}

// Front: blocks [0,128) = sigmoid + separable 11x11 max + peak emit (private
// candidate regions). Blocks [128,256) = all zero-fills (run concurrently).
__global__ __launch_bounds__(256) void k_front(const float* __restrict__ x4,
        unsigned long long* __restrict__ cand,
        unsigned long long* __restrict__ packed,
        unsigned long long* __restrict__ bitsG,
        float* __restrict__ areas, float* __restrict__ msum,
        int* __restrict__ iy0, int* __restrict__ ix0,
        int* __restrict__ rankbuf, int* __restrict__ cnt) {
    int tid = threadIdx.x, bid = blockIdx.x;
    if (bid < NFRONT) {
        __shared__ float vm[RPB][WWI];
        __shared__ int lcnt;
        int r0 = bid * RPB;
        if (tid == 0) lcnt = 0;
        if (tid < CPB) cand[bid * CPB + tid] = 0ull;
        float s0[SROWS], s1[SROWS];
        #pragma unroll
        for (int hr = 0; hr < SROWS; ++hr) {
            int gr = r0 - HALO + hr; gr = gr < 0 ? 0 : (gr > HH-1 ? HH-1 : gr);
            const float* row = x4 + gr * WWI;
            s0[hr] = sigm(row[tid]);
            s1[hr] = sigm(row[tid + 256]);
        }
        #pragma unroll
        for (int rr = 0; rr < RPB; ++rr) {
            float a = s0[rr], b = s1[rr];
            #pragma unroll
            for (int d = 1; d < 11; ++d) { a = fmaxf(a, s0[rr+d]); b = fmaxf(b, s1[rr+d]); }
            vm[rr][tid] = a; vm[rr][tid + 256] = b;
        }
        __syncthreads();
        #pragma unroll
        for (int rr = 0; rr < RPB; ++rr) {
            int gy = r0 + rr;
            {
                int c = tid;
                float m = s0[rr + HALO];
                if (m > 0.7f) {
                    int c0 = c-5 < 0 ? 0 : c-5, c1 = c+5;
                    float v = -1.0f;
                    for (int cc = c0; cc <= c1; ++cc) v = fmaxf(v, vm[rr][cc]);
                    if (m == v) {
                        int slot = atomicAdd(&lcnt, 1);
                        if (slot < CPB) {
                            unsigned p = (unsigned)(gy * WWI + c);
                            cand[bid * CPB + slot] =
                                ((unsigned long long)__float_as_uint(m) << 32) |
                                (unsigned long long)(0xFFFFFFFFu - p);
                        }
                    }
                }
            }
            {
                int c = tid + 256;
                float m = s1[rr + HALO];
                if (m > 0.7f) {
                    int c0 = c-5, c1 = c+5 > 511 ? 511 : c+5;
                    float v = -1.0f;
                    for (int cc = c0; cc <= c1; ++cc) v = fmaxf(v, vm[rr][cc]);
                    if (m == v) {
                        int slot = atomicAdd(&lcnt, 1);
                        if (slot < CPB) {
                            unsigned p = (unsigned)(gy * WWI + c);
                            cand[bid * CPB + slot] =
                                ((unsigned long long)__float_as_uint(m) << 32) |
                                (unsigned long long)(0xFFFFFFFFu - p);
                        }
                    }
                }
            }
        }
    } else {
        int gt = (bid - NFRONT) * 256 + tid;       // [0, 32768)
        ulonglong2 z; z.x = 0ull; z.y = 0ull;
        // packed: 262144 u64 -> 8 per thread
        ulonglong2* p2 = (ulonglong2*)(packed + (size_t)gt * 8);
        p2[0] = z; p2[1] = z; p2[2] = z; p2[3] = z;
        // bitsG: 131072 u64 -> 4 per thread
        ulonglong2* b2 = (ulonglong2*)(bitsG + (size_t)gt * 4);
        b2[0] = z; b2[1] = z;
        if (gt < CAND_CAP) rankbuf[gt] = 0;
        if (gt < KK) { areas[gt] = 0.0f; msum[gt] = 0.0f; iy0[gt] = 0; ix0[gt] = 0; }
        if (gt == 0) *cnt = 0;
    }
}

// Tiled rank precompute: block (bx,by) ranks chunk bx against key chunk by
// (LDS-staged); also accumulates the valid-candidate count (by==0 row).
__global__ __launch_bounds__(256) void k_rank(const unsigned long long* __restrict__ cand,
                                              int* __restrict__ rankbuf,
                                              int* __restrict__ cnt) {
    __shared__ unsigned long long kl[256];
    int tid = threadIdx.x;
    int bx = blockIdx.x & 15, by = blockIdx.x >> 4;
    int ibase = bx * 256, jbase = by * 256;
    kl[tid] = cand[jbase + tid];
    unsigned long long my = cand[ibase + tid];
    if (by == 0) {
        unsigned long long bal = __ballot(my != 0ull);
        if ((tid & 63) == 0) atomicAdd(cnt, (int)__popcll(bal));
    }
    __syncthreads();
    if (my == 0ull) return;
    int r0 = 0, r1 = 0, r2 = 0, r3 = 0, r4 = 0, r5 = 0, r6 = 0, r7 = 0;
    #pragma unroll 4
    for (int j = 0; j < 256; j += 8) {
        unsigned long long a0 = kl[j+0], a1 = kl[j+1], a2 = kl[j+2], a3 = kl[j+3];
        unsigned long long a4 = kl[j+4], a5 = kl[j+5], a6 = kl[j+6], a7 = kl[j+7];
        r0 += (a0 > my); r1 += (a1 > my); r2 += (a2 > my); r3 += (a3 > my);
        r4 += (a4 > my); r5 += (a5 > my); r6 += (a6 > my); r7 += (a7 > my);
    }
    int r = (r0 + r1) + (r2 + r3) + ((r4 + r5) + (r6 + r7));
    if (r) atomicAdd(&rankbuf[ibase + tid], r);
}

// Windowed classifier: SUB=4 sub-blocks per candidate, 16 rows each (4x the
// window-phase parallelism). Coalesced loads/stores; ballot row-bitmaps into
// global-row bitsG[gy][k]; packed 64-bit atomicMax fuses winner labeling.
// areas: integer-valued float atomicAdds (exact, order-independent).
__global__ __launch_bounds__(256) void k_win2(const float* __restrict__ x,
        const float* __restrict__ wc, const float* __restrict__ bc,
        const unsigned long long* __restrict__ cand,
        const int* __restrict__ rankbuf, const int* __restrict__ cnt,
        float* __restrict__ probs, unsigned long long* __restrict__ packed,
        unsigned long long* __restrict__ bitsG,
        float* __restrict__ areas, float* __restrict__ msum,
        int* __restrict__ iy0, int* __restrict__ ix0) {
    int bid = blockIdx.x, tid = threadIdx.x;
    int lane = tid & 63;
    if (bid >= SUB * CAND_CAP) {       // tail: zero unfilled prob slots
        int j = bid - SUB * CAND_CAP;
        int c = *cnt; if (c > KK) c = KK;
        if (j >= c) for (int i = tid; i < 4096; i += 256) probs[j * 4096 + i] = 0.0f;
        return;
    }
    int c = bid >> 2, sub = bid & 3;
    unsigned long long my = cand[c];
    if (my == 0ull) return;
    int k = rankbuf[c];
    if (k >= KK) return;

    unsigned pp = 0xFFFFFFFFu - (unsigned)(my & 0xFFFFFFFFull);
    int cy = (int)(pp >> 9), cx = (int)(pp & 511);
    int wy = cy < WSR ? WSR : (cy > HH - WSR ? HH - WSR : cy);
    int wx = cx < WSR ? WSR : (cx > WWI - WSR ? WWI - WSR : cx);
    int gy0 = wy - WSR, gx0 = wx - WSR;
    if (sub == 0 && tid == 0) { iy0[k] = gy0; ix0[k] = gx0; }

    __shared__ float sA, sM;
    if (tid == 0) { sA = 0.0f; sM = 0.0f; }
    __syncthreads();
    float w0 = wc[0], w1 = wc[1], w2 = wc[2], w3 = wc[3], b = bc[0];
    float cyf = (float)cy, cxf = (float)cx;
    const float* x0 = x;
    const float* x1 = x + HWN;
    const float* x2 = x + 2 * HWN;
    const float* x3 = x + 3 * HWN;
    const float* x4 = x + 4 * HWN;
    unsigned long long idbits = (unsigned long long)(unsigned)(k + 1);
    float aA = 0.0f, aM = 0.0f;
    #pragma unroll
    for (int q = 0; q < 4; ++q) {
        int p = (((sub << 2) + q) << 8) + tid;   // sub*1024 + q*256 + tid
        int row = p >> 6;              // uniform per wave
        int col = p & 63;              // = lane
        int gy = gy0 + row, gx = gx0 + col;
        int g = gy * WWI + gx;
        float gyf = (float)gy;
        float d0 = __fsub_rn(__fadd_rn(x0[g], gyf), cyf);
        float d1 = __fsub_rn(__fadd_rn(x1[g], (float)gx), cxf);
        float s0v = x2[g], s1v = x3[g];
        float t = __fadd_rn(
                    __fadd_rn(
                      __fadd_rn(
                        __fadd_rn(__fmul_rn(w0, d0), __fmul_rn(w1, d1)),
                        __fmul_rn(w2, s0v)),
                      __fmul_rn(w3, s1v)),
                    b);
        float pr = sigm(t);
        probs[k * 4096 + p] = pr;
        bool pass = pr > 0.53f;
        unsigned long long bal = __ballot(pass);
        if (lane == 0) bitsG[(size_t)gy * 256 + k] = bal;
        if (pass) {
            aA += 1.0f;
            aM += sigm(x4[g]);
            atomicMax(&packed[g],
                      ((unsigned long long)__float_as_uint(pr) << 32) | idbits);
        }
    }
    #pragma unroll
    for (int off = 32; off; off >>= 1) {
        aA += __shfl_down(aA, off);
        aM += __shfl_down(aM, off);
    }
    if (lane == 0) { atomicAdd(&sA, aA); atomicAdd(&sM, aM); }
    __syncthreads();
    if (tid == 0) { atomicAdd(&areas[k], sA); atomicAdd(&msum[k], sM); }
}

// Pairwise IoU adjacency, coalesced: wb = bitsG[gy*256 + b2] is consecutive
// across lanes; wa is a uniform broadcast. Rows outside b's window read 0.
__global__ __launch_bounds__(256) void k_pairs(
        const unsigned long long* __restrict__ bitsG,
        const float* __restrict__ areas,
        const int* __restrict__ iy0, const int* __restrict__ ix0,
        unsigned long long* __restrict__ adj) {
    int a = blockIdx.x, tid = threadIdx.x;
    int b2 = tid;
    int ay0 = iy0[a], ax0 = ix0[a];
    int bx0 = ix0[b2];
    int xl = max(ax0, bx0), xh = min(ax0 + SSW, bx0 + SSW);
    int inter = 0;
    if (xl < xh) {
        int wdt = xh - xl;
        unsigned long long cmask = (wdt >= 64) ? ~0ull : ((1ull << wdt) - 1ull);
        int sa = xl - ax0, sb = xl - bx0;
        for (int i = 0; i < SSW; ++i) {
            int gy = ay0 + i;
            unsigned long long wa = bitsG[(size_t)gy * 256 + a];   // uniform
            unsigned long long wb = bitsG[(size_t)gy * 256 + b2];  // coalesced
            inter += __popcll((wa >> sa) & (wb >> sb) & cmask);
        }
    }
    float fi = (float)inter;
    float uni = __fsub_rn(__fadd_rn(areas[a], areas[b2]), fi);
    bool adjb = (fi / fmaxf(uni, 1.0f)) > 0.3f;
    unsigned long long bal = __ballot(adjb);
    if ((tid & 63) == 0) adj[a * 4 + (tid >> 6)] = bal;
}

// Final: every block redundantly computes CC+filter in LDS (identical result,
// deterministic), then relabels its 1024 pixels (4 px/thread, vectorized).
__global__ __launch_bounds__(256) void k_final(
        const unsigned long long* __restrict__ packed,
        const int* __restrict__ cnt,
        const unsigned long long* __restrict__ adj,
        const float* __restrict__ areas, const float* __restrict__ msum,
        float* __restrict__ labels) {
    __shared__ unsigned long long adjS[KK][4];
    __shared__ int lbl[KK];
    __shared__ int fmS[KK];
    __shared__ unsigned char rem[KK];
    __shared__ int changed;
    int tid = threadIdx.x;
    for (int w = 0; w < 4; ++w) adjS[tid][w] = adj[tid * 4 + w];
    lbl[tid] = tid;
    __syncthreads();
    int cntv = *cnt;
    for (int it = 0; it < 32; ++it) {
        int m = KK;
        for (int w = 0; w < 4; ++w) {
            unsigned long long bb = adjS[tid][w];
            while (bb) {
                int j = __ffsll((unsigned long long)bb) - 1;
                int v = lbl[(w << 6) | j];
                m = v < m ? v : m;
                bb &= bb - 1;
            }
        }
        if (tid == 0) changed = 0;
        __syncthreads();
        if (m != lbl[tid]) { lbl[tid] = m; atomicOr(&changed, 1); }
        __syncthreads();
        if (!changed) break;
    }
    float area = areas[tid];
    bool validf = tid < cntv;
    float mean = msum[tid] / fmaxf(area, 1.0f);
    rem[tid] = (unsigned char)(!((mean > 0.0f) && (area > 10.0f) && validf));
    __syncthreads();
    {
        int root = lbl[tid];
        int rc = root < 255 ? root : 255;
        fmS[tid] = rem[rc] ? 0 : (root + 1);
    }
    __syncthreads();

    int i = blockIdx.x * 256 + tid;                 // [0, 65536)
    const ulonglong2* p2 = (const ulonglong2*)(packed + (size_t)i * 4);
    ulonglong2 a = p2[0], b = p2[1];
    float4 o;
    unsigned l0 = (unsigned)(a.x & 0xFFFFFFFFull);
    unsigned l1 = (unsigned)(a.y & 0xFFFFFFFFull);
    unsigned l2 = (unsigned)(b.x & 0xFFFFFFFFull);
    unsigned l3 = (unsigned)(b.y & 0xFFFFFFFFull);
    o.x = l0 ? (float)fmS[l0 - 1] : 0.0f;
    o.y = l1 ? (float)fmS[l1 - 1] : 0.0f;
    o.z = l2 ? (float)fmS[l2 - 1] : 0.0f;
    o.w = l3 ? (float)fmS[l3 - 1] : 0.0f;
    *(float4*)(labels + (size_t)i * 4) = o;
}

extern "C" void kernel_launch(void* const* d_in, const int* in_sizes, int n_in,
                              void* d_out, int out_size, void* d_ws, size_t ws_size,
                              hipStream_t stream) {
    const float* x  = (const float*)d_in[0];
    const float* wc = (const float*)d_in[1];
    const float* bc = (const float*)d_in[2];
    float* labels = (float*)d_out;
    float* probs  = (float*)d_out + HWN;

    char* ws = (char*)d_ws;
    unsigned long long* packed  = (unsigned long long*)(ws + OFF_PACKED);
    unsigned long long* bitsG   = (unsigned long long*)(ws + OFF_BITSG);
    float*              areas   = (float*)(ws + OFF_AREA);
    float*              msum    = (float*)(ws + OFF_MSUM);
    int*                iy0p    = (int*)(ws + OFF_WY0);
    int*                ix0p    = (int*)(ws + OFF_WX0);
    unsigned long long* adj     = (unsigned long long*)(ws + OFF_ADJ);
    unsigned long long* cand    = (unsigned long long*)(ws + OFF_CAND);
    int*                rankbuf = (int*)(ws + OFF_RANK);
    int*                cnt     = (int*)(ws + OFF_CNT);

    k_front<<<256, 256, 0, stream>>>(x + 4 * HWN, cand, packed, bitsG,
                                     areas, msum, iy0p, ix0p, rankbuf, cnt);
    k_rank <<<256, 256, 0, stream>>>(cand, rankbuf, cnt);
    k_win2 <<<SUB * CAND_CAP + KK, 256, 0, stream>>>(x, wc, bc, cand, rankbuf, cnt,
                                                     probs, packed, bitsG,
                                                     areas, msum, iy0p, ix0p);
    k_pairs<<<KK, 256, 0, stream>>>(bitsG, areas, iy0p, ix0p, adj);
    k_final<<<HWN / 1024, 256, 0, stream>>>(packed, cnt, adj, areas, msum, labels);
}